// Round 9
// baseline (70.825 us; speedup 1.0000x reference)
//
#include <hip/hip_runtime.h>
#include <math.h>

#define NB   4
#define HH   64
#define WW   64
#define CCH  256
#define GG   8
#define CGC  32
#define HI   66
#define NPIX 16384
#define OMWS 256   // offm row stride: 144 off + 72 mask + 40 pad

typedef unsigned short ushort_t;
typedef __attribute__((ext_vector_type(8))) short short8;
typedef __attribute__((ext_vector_type(4))) float floatx4;

__device__ inline ushort_t f2bf(float f) {
    union { float f; unsigned u; } v; v.f = f;
    unsigned r = v.u + 0x7FFF + ((v.u >> 16) & 1);   // round-to-nearest-even
    return (ushort_t)(r >> 16);
}
__device__ inline float bf2f(ushort_t u) {
    union { unsigned u; float f; } v; v.u = ((unsigned)u) << 16; return v.f;
}

__device__ inline void gload_lds16(const ushort_t* g, ushort_t* l) {
    __builtin_amdgcn_global_load_lds(
        (const __attribute__((address_space(1))) void*)g,
        (__attribute__((address_space(3))) void*)l, 16, 0, 0);
}

// ---------------- bf16 MFMA GEMM: C[M,256] = A[M,256] @ B[256,256] + bias ----
// BK=128, bf16 A. MODE 0: fp32 out[row*256+col].
template<int MODE>
__global__ __launch_bounds__(256)
void gemm_mfma(const ushort_t* __restrict__ A, const ushort_t* __restrict__ Bt,
               const float* __restrict__ bias, void* __restrict__ outv)
{
    __shared__ ushort_t As[64 * 128];   // 16 KB
    __shared__ ushort_t Bs[64 * 128];   // 16 KB
    const int tid  = threadIdx.x;
    const int lane = tid & 63, wid = tid >> 6;
    const int wr = wid >> 1, wc = wid & 1;
    const int q = lane >> 4, r = lane & 15;
    const int row0 = blockIdx.x * 64, col0 = blockIdx.y * 64;

    floatx4 acc[2][2] = {};

    #pragma unroll 1
    for (int kt = 0; kt < 2; ++kt) {
        #pragma unroll
        for (int j = 0; j < 4; ++j) {
            int gi = j * 256 + tid;            // 0..1023
            int arow = gi >> 4, gk = gi & 15;  // row, k-granule(16B)
            int src = kt * 128 + ((gk ^ (arow & 7)) * 8);
            gload_lds16(A  + (size_t)(row0 + arow) * 256 + src, As + gi * 8);
            gload_lds16(Bt + (size_t)(col0 + arow) * 256 + src, Bs + gi * 8);
        }
        __syncthreads();
        #pragma unroll
        for (int kk = 0; kk < 4; ++kk) {
            short8 af[2], bf[2];
            const int gsw = ((kk * 4 + q) ^ (r & 7)) * 8;
            #pragma unroll
            for (int m = 0; m < 2; ++m) {
                af[m] = *(const short8*)&As[(wr * 32 + m * 16 + r) * 128 + gsw];
                bf[m] = *(const short8*)&Bs[(wc * 32 + m * 16 + r) * 128 + gsw];
            }
            #pragma unroll
            for (int m = 0; m < 2; ++m)
                #pragma unroll
                for (int n = 0; n < 2; ++n)
                    acc[m][n] = __builtin_amdgcn_mfma_f32_16x16x32_bf16(
                                    af[m], bf[n], acc[m][n], 0, 0, 0);
        }
        __syncthreads();
    }

    #pragma unroll
    for (int m = 0; m < 2; ++m) {
        #pragma unroll
        for (int n = 0; n < 2; ++n) {
            #pragma unroll
            for (int j = 0; j < 4; ++j) {
                int row = row0 + wr * 32 + m * 16 + q * 4 + j;
                int col = col0 + wc * 32 + n * 16 + r;
                ((float*)outv)[(size_t)row * 256 + col] = acc[m][n][j] + bias[col];
            }
        }
    }
}

// ---------------- merged: zero pad ring (bf16) + pack weights ----------------
__global__ __launch_bounds__(256)
void ring_pack(ushort_t* __restrict__ xpadb,
               const float* __restrict__ in_w, const float* __restrict__ out_w,
               const float* __restrict__ off_w, const float* __restrict__ mask_w,
               const float* __restrict__ off_b, const float* __restrict__ mask_b,
               const float* __restrict__ dw_k, const float* __restrict__ bn_g,
               const float* __restrict__ bn_b, const float* __restrict__ bn_m,
               const float* __restrict__ bn_v,
               ushort_t* __restrict__ WtIn, ushort_t* __restrict__ WtOut,
               ushort_t* __restrict__ W2t, float* __restrict__ b2,
               float* __restrict__ dwkT, float* __restrict__ bnS,
               float* __restrict__ bnB)
{
    int bid = blockIdx.x;
    if (bid < NB * 260) {
        int n = bid / 260, rp = bid % 260;
        int h, w;
        if (rp < 66)       { h = 0;              w = rp; }
        else if (rp < 132) { h = 65;             w = rp - 66; }
        else if (rp < 196) { h = 1 + (rp - 132); w = 0; }
        else               { h = 1 + (rp - 196); w = 65; }
        xpadb[(size_t)((n * HI + h) * HI + w) * CCH + threadIdx.x] = 0;
        return;
    }
    int n = bid - NB * 260, k = threadIdx.x;
    WtIn [n * 256 + k] = f2bf(in_w [k * 256 + n]);
    WtOut[n * 256 + k] = f2bf(out_w[k * 256 + n]);
    float w2 = (n < 144) ? off_w[k * 144 + n]
             : (n < 216) ? mask_w[k * 72 + (n - 144)] : 0.f;
    W2t[n * 256 + k] = f2bf(w2);
    if (k == 0) b2[n] = (n < 144) ? off_b[n] : (n < 216) ? mask_b[n - 144] : 0.f;
    if (k < 9) dwkT[k * 256 + n] = dw_k[n * 9 + k];   // tap-major
    if (k == 9) {
        float s = bn_g[n] * rsqrtf(bn_v[n] + 1e-5f);
        bnS[n] = s;
        bnB[n] = bn_b[n] - bn_m[n] * s;
    }
}

// ---------------- heterogeneous dispatch: input-proj GEMM + depthwise conv ----
// Blocks 0..1023: gemm1 (A = fp32 x, cvt-while-staging; out bf16 xpadb interior)
// Blocks 1024..5119: depthwise 3x3 + BN + SiLU -> bf16 x1b (4 pixels/block)
__global__ __launch_bounds__(256)
void dw_in_proj(const float* __restrict__ x, const ushort_t* __restrict__ Bt,
                const float* __restrict__ bias, const float* __restrict__ dwkT,
                const float* __restrict__ bnS, const float* __restrict__ bnB,
                ushort_t* __restrict__ xpadb, ushort_t* __restrict__ x1b)
{
    __shared__ ushort_t As[64 * 128];   // 16 KB
    __shared__ ushort_t Bs[64 * 128];   // 16 KB
    const int tid = threadIdx.x;

    if (blockIdx.x < 1024) {
        // ---------------- input-projection GEMM ----------------
        const int lane = tid & 63, wid = tid >> 6;
        const int wr = wid >> 1, wc = wid & 1;
        const int q = lane >> 4, r = lane & 15;
        const int row0 = (blockIdx.x & 255) * 64, col0 = (blockIdx.x >> 8) * 64;

        floatx4 acc[2][2] = {};

        #pragma unroll 1
        for (int kt = 0; kt < 2; ++kt) {
            #pragma unroll
            for (int j = 0; j < 4; ++j) {
                int gi = j * 256 + tid;
                int arow = gi >> 4, gk = gi & 15;
                int src = kt * 128 + ((gk ^ (arow & 7)) * 8);
                // A: fp32 -> bf16 while staging (reg -> ds_write)
                const float* xa = x + (size_t)(row0 + arow) * 256 + src;
                float4 f0 = *reinterpret_cast<const float4*>(xa);
                float4 f1 = *reinterpret_cast<const float4*>(xa + 4);
                ushort_t cv[8] = { f2bf(f0.x), f2bf(f0.y), f2bf(f0.z), f2bf(f0.w),
                                   f2bf(f1.x), f2bf(f1.y), f2bf(f1.z), f2bf(f1.w) };
                *reinterpret_cast<short8*>(As + gi * 8) = *reinterpret_cast<short8*>(cv);
                gload_lds16(Bt + (size_t)(col0 + arow) * 256 + src, Bs + gi * 8);
            }
            __syncthreads();
            #pragma unroll
            for (int kk = 0; kk < 4; ++kk) {
                short8 af[2], bf[2];
                const int gsw = ((kk * 4 + q) ^ (r & 7)) * 8;
                #pragma unroll
                for (int m = 0; m < 2; ++m) {
                    af[m] = *(const short8*)&As[(wr * 32 + m * 16 + r) * 128 + gsw];
                    bf[m] = *(const short8*)&Bs[(wc * 32 + m * 16 + r) * 128 + gsw];
                }
                #pragma unroll
                for (int m = 0; m < 2; ++m)
                    #pragma unroll
                    for (int n = 0; n < 2; ++n)
                        acc[m][n] = __builtin_amdgcn_mfma_f32_16x16x32_bf16(
                                        af[m], bf[n], acc[m][n], 0, 0, 0);
            }
            __syncthreads();
        }

        #pragma unroll
        for (int m = 0; m < 2; ++m) {
            #pragma unroll
            for (int n = 0; n < 2; ++n) {
                #pragma unroll
                for (int j = 0; j < 4; ++j) {
                    int row = row0 + wr * 32 + m * 16 + q * 4 + j;
                    int col = col0 + wc * 32 + n * 16 + r;
                    float v = acc[m][n][j] + bias[col];
                    int nn = row >> 12, hh = (row >> 6) & 63, www = row & 63;
                    xpadb[(size_t)((nn * HI + hh + 1) * HI + (www + 1)) * CCH + col] = f2bf(v);
                }
            }
        }
    } else {
        // ---------------- depthwise conv + BN + SiLU ----------------
        const int lane = tid & 63, wvid = tid >> 6;
        const int pix = (blockIdx.x - 1024) * 4 + wvid;
        const int n = pix >> 12, hw = pix & 4095, h = hw >> 6, w = hw & 63;
        const int c4 = lane << 2;

        const float4 cv = *reinterpret_cast<const float4*>(x + (size_t)pix * CCH + c4);
        const float4 kc = *reinterpret_cast<const float4*>(dwkT + 4 * 256 + c4);
        float ax = cv.x * kc.x, ay = cv.y * kc.y, az = cv.z * kc.z, aw = cv.w * kc.w;

        #pragma unroll
        for (int tap = 0; tap < 9; ++tap) {
            if (tap == 4) continue;
            int hh = h + tap / 3 - 1, ww = w + tap % 3 - 1;
            if ((unsigned)hh < HH && (unsigned)ww < WW) {
                const float4 v = *reinterpret_cast<const float4*>(
                    x + (size_t)((n * HH + hh) * WW + ww) * CCH + c4);
                const float4 kk = *reinterpret_cast<const float4*>(dwkT + tap * 256 + c4);
                ax += v.x * kk.x; ay += v.y * kk.y; az += v.z * kk.z; aw += v.w * kk.w;
            }
        }
        const float4 s = *reinterpret_cast<const float4*>(bnS + c4);
        const float4 b = *reinterpret_cast<const float4*>(bnB + c4);
        float yx = ax * s.x + b.x, yy = ay * s.y + b.y;
        float yz = az * s.z + b.z, yw = aw * s.w + b.w;
        yx = yx / (1.f + __expf(-yx));
        yy = yy / (1.f + __expf(-yy));
        yz = yz / (1.f + __expf(-yz));
        yw = yw / (1.f + __expf(-yw));
        ushort_t o[4] = { f2bf(yx), f2bf(yy), f2bf(yz), f2bf(yw) };
        *reinterpret_cast<ushort4*>(x1b + (size_t)pix * CCH + c4) = *reinterpret_cast<ushort4*>(o);
    }
}

// ---------------- DCNv3 core: softmax + bilinear sampling on bf16 image -------
__global__ __launch_bounds__(256)
void dcn_sample(const ushort_t* __restrict__ xpadb, const float* __restrict__ om,
                ushort_t* __restrict__ coreb)
{
    const int tid = threadIdx.x;
    const int pix = blockIdx.x * 8 + (tid >> 5);
    const int l   = tid & 31;
    const int g = l >> 2, c8 = (l & 3) << 3;
    const int n = pix >> 12, hw = pix & 4095, h = hw >> 6, w = hw & 63;
    const float* __restrict__ omp = om + (size_t)pix * OMWS;

    float lg[9], mx = -1e30f;
    #pragma unroll
    for (int p = 0; p < 9; ++p) { lg[p] = omp[144 + g * 9 + p]; mx = fmaxf(mx, lg[p]); }
    float s = 0.f;
    #pragma unroll
    for (int p = 0; p < 9; ++p) { lg[p] = __expf(lg[p] - mx); s += lg[p]; }
    const float inv = 1.f / s;

    const ushort_t* __restrict__ img = xpadb + (size_t)n * HI * HI * CCH + g * CGC + c8;
    float acc[8] = {};
    #pragma unroll
    for (int p = 0; p < 9; ++p) {
        float ox = omp[g * 18 + p * 2 + 0];
        float oy = omp[g * 18 + p * 2 + 1];
        float xi = (float)(w + (p / 3)) + ox;
        float yi = (float)(h + (p % 3)) + oy;
        float x0f = floorf(xi), y0f = floorf(yi);
        int x0 = (int)x0f, y0 = (int)y0f;
        float fx = xi - x0f, fy = yi - y0f;
        float wgt = lg[p] * inv;
        float cw[4] = { (1.f - fx) * (1.f - fy) * wgt, fx * (1.f - fy) * wgt,
                        (1.f - fx) * fy * wgt,         fx * fy * wgt };
        #pragma unroll
        for (int cr = 0; cr < 4; ++cr) {
            int xc = x0 + (cr & 1), yc = y0 + (cr >> 1);
            if ((unsigned)xc < HI && (unsigned)yc < HI) {
                short8 raw = *reinterpret_cast<const short8*>(img + (size_t)(yc * HI + xc) * CCH);
                float wc = cw[cr];
                #pragma unroll
                for (int j = 0; j < 8; ++j) acc[j] += wc * bf2f((ushort_t)raw[j]);
            }
        }
    }
    ushort_t o[8];
    #pragma unroll
    for (int j = 0; j < 8; ++j) o[j] = f2bf(acc[j]);
    *reinterpret_cast<short8*>(coreb + (size_t)pix * CCH + g * CGC + c8) =
        *reinterpret_cast<short8*>(o);
}

extern "C" void kernel_launch(void* const* d_in, const int* in_sizes, int n_in,
                              void* d_out, int out_size, void* d_ws, size_t ws_size,
                              hipStream_t stream) {
    const float* x      = (const float*)d_in[0];
    const float* in_w   = (const float*)d_in[1];
    const float* in_b   = (const float*)d_in[2];
    const float* out_w  = (const float*)d_in[3];
    const float* out_b  = (const float*)d_in[4];
    const float* off_w  = (const float*)d_in[5];
    const float* off_b  = (const float*)d_in[6];
    const float* mask_w = (const float*)d_in[7];
    const float* mask_b = (const float*)d_in[8];
    const float* dw_k   = (const float*)d_in[9];
    const float* bn_g   = (const float*)d_in[10];
    const float* bn_b   = (const float*)d_in[11];
    const float* bn_m   = (const float*)d_in[12];
    const float* bn_v   = (const float*)d_in[13];

    float* ws = (float*)d_ws;
    float*    offm  = ws;                                  // 16384*256 f
    ushort_t* xpadb = (ushort_t*)(offm + 4194304);         // 4,460,544 us
    ushort_t* x1b   = xpadb + 4460544;                     // 4,194,304 us
    ushort_t* coreb = x1b + 4194304;
    ushort_t* WtIn  = coreb + 4194304;                     // 65,536 us
    ushort_t* WtOut = WtIn + 65536;
    ushort_t* W2t   = WtOut + 65536;
    float*    b2    = (float*)(W2t + 65536);               // 256 f
    float*    dwkT  = b2 + 256;                            // 9*256 f
    float*    bnS   = dwkT + 9 * 256;                      // 256 f
    float*    bnB   = bnS + 256;                           // 256 f

    // zero pad ring + pack all weights (one launch)
    ring_pack<<<NB * 260 + 256, 256, 0, stream>>>(xpadb,
        in_w, out_w, off_w, mask_w, off_b, mask_b,
        dw_k, bn_g, bn_b, bn_m, bn_v,
        WtIn, WtOut, W2t, b2, dwkT, bnS, bnB);

    // 1+2) heterogeneous: input-proj GEMM (cvt-while-staging) + depthwise conv
    dw_in_proj<<<1024 + NPIX / 4, 256, 0, stream>>>(x, WtIn, in_b, dwkT, bnS, bnB,
                                                    xpadb, x1b);

    // 3) offset + mask projection (fused, N padded to 256)
    gemm_mfma<0><<<dim3(NPIX / 64, 4), 256, 0, stream>>>(x1b, W2t, b2, offm);

    // 4) deformable sampling on bf16 image (2 px/wave, 16B gathers)
    dcn_sample<<<NPIX / 8, 256, 0, stream>>>(xpadb, offm, coreb);

    // 5) output projection -> d_out
    gemm_mfma<0><<<dim3(NPIX / 64, 4), 256, 0, stream>>>(coreb, WtOut, out_b, (float*)d_out);
}

// Round 10
// 66.602 us; speedup vs baseline: 1.0634x; 1.0634x over previous
//
#include <hip/hip_runtime.h>
#include <math.h>

#define NB   4
#define HH   64
#define WW   64
#define CCH  256
#define GG   8
#define CGC  32
#define HI   66
#define NPIX 16384
#define OMWS 256   // offm row stride: 144 off + 72 mask + 40 pad

typedef unsigned short ushort_t;
typedef __attribute__((ext_vector_type(8))) short short8;
typedef __attribute__((ext_vector_type(4))) float floatx4;

__device__ inline ushort_t f2bf(float f) {
    union { float f; unsigned u; } v; v.f = f;
    unsigned r = v.u + 0x7FFF + ((v.u >> 16) & 1);   // round-to-nearest-even
    return (ushort_t)(r >> 16);
}
__device__ inline float bf2f(ushort_t u) {
    union { unsigned u; float f; } v; v.u = ((unsigned)u) << 16; return v.f;
}

__device__ inline void gload_lds16(const ushort_t* g, ushort_t* l) {
    __builtin_amdgcn_global_load_lds(
        (const __attribute__((address_space(1))) void*)g,
        (__attribute__((address_space(3))) void*)l, 16, 0, 0);
}

// ---------------- bf16 MFMA GEMM: C[M,256] = A[M,256] @ Bt[256n][256k] + bias
// 128x64 tile, 4 waves (each 32 rows x 64 cols, acc[2][4]), BK=64,
// double-buffered LDS with next-tile prefetch, 1 barrier per K-step.
// MODE 0: fp32 out[row*256+col]. MODE 1: bf16 xpad interior. MODE 2: bf16 linear.
template<int MODE>
__global__ __launch_bounds__(256)
void gemm_mfma(const ushort_t* __restrict__ A, const ushort_t* __restrict__ Bt,
               const float* __restrict__ bias, void* __restrict__ outv)
{
    __shared__ ushort_t As[2][128 * 64];   // 2 x 16 KB
    __shared__ ushort_t Bs[2][64 * 64];    // 2 x  8 KB
    const int tid  = threadIdx.x;
    const int lane = tid & 63, wid = tid >> 6;
    const int q = lane >> 4, r = lane & 15;
    // bijective XCD swizzle (nwg=512, 512%8==0); col-fast so each XCD keeps
    // a contiguous A-row panel in its L2.
    const int bid = blockIdx.x;
    const int swz = (bid & 7) * 64 + (bid >> 3);
    const int row0 = (swz >> 2) * 128, col0 = (swz & 3) * 64;

    floatx4 acc[2][4] = {};

    auto stage = [&](int buf, int kt) {
        #pragma unroll
        for (int j = 0; j < 4; ++j) {              // A: 1024 granules, 4/thread
            int gi = j * 256 + tid;
            int arow = gi >> 3, gk = gi & 7;
            gload_lds16(A + (size_t)(row0 + arow) * 256 + kt * 64 + ((gk ^ (arow & 7)) * 8),
                        &As[buf][gi * 8]);
        }
        #pragma unroll
        for (int j = 0; j < 2; ++j) {              // B: 512 granules, 2/thread
            int gi = j * 256 + tid;
            int brow = gi >> 3, gk = gi & 7;
            gload_lds16(Bt + (size_t)(col0 + brow) * 256 + kt * 64 + ((gk ^ (brow & 7)) * 8),
                        &Bs[buf][gi * 8]);
        }
    };

    stage(0, 0);
    __syncthreads();
    int cur = 0;
    #pragma unroll 1
    for (int kt = 0; kt < 4; ++kt) {
        if (kt < 3) stage(cur ^ 1, kt + 1);        // prefetch next tile
        #pragma unroll
        for (int kk = 0; kk < 2; ++kk) {
            short8 af[2], bf[4];
            const int gsw = ((kk * 4 + q) ^ (r & 7)) * 8;
            #pragma unroll
            for (int m = 0; m < 2; ++m)
                af[m] = *(const short8*)&As[cur][(wid * 32 + m * 16 + r) * 64 + gsw];
            #pragma unroll
            for (int n = 0; n < 4; ++n)
                bf[n] = *(const short8*)&Bs[cur][(n * 16 + r) * 64 + gsw];
            #pragma unroll
            for (int m = 0; m < 2; ++m)
                #pragma unroll
                for (int n = 0; n < 4; ++n)
                    acc[m][n] = __builtin_amdgcn_mfma_f32_16x16x32_bf16(
                                    af[m], bf[n], acc[m][n], 0, 0, 0);
        }
        __syncthreads();                           // drains prefetch, releases buffers
        cur ^= 1;
    }

    #pragma unroll
    for (int m = 0; m < 2; ++m) {
        #pragma unroll
        for (int n = 0; n < 4; ++n) {
            #pragma unroll
            for (int j = 0; j < 4; ++j) {
                int row = row0 + wid * 32 + m * 16 + q * 4 + j;
                int col = col0 + n * 16 + r;
                float v = acc[m][n][j] + bias[col];
                if (MODE == 1) {
                    int nn = row >> 12, hh = (row >> 6) & 63, www = row & 63;
                    ((ushort_t*)outv)[(size_t)((nn * HI + hh + 1) * HI + (www + 1)) * CCH + col] = f2bf(v);
                } else if (MODE == 2) {
                    ((ushort_t*)outv)[(size_t)row * 256 + col] = f2bf(v);
                } else {
                    ((float*)outv)[(size_t)row * 256 + col] = v;
                }
            }
        }
    }
}

// ---------------- merged: zero pad ring (bf16) + pack weights ----------------
__global__ __launch_bounds__(256)
void ring_pack(ushort_t* __restrict__ xpadb,
               const float* __restrict__ in_w, const float* __restrict__ out_w,
               const float* __restrict__ off_w, const float* __restrict__ mask_w,
               const float* __restrict__ off_b, const float* __restrict__ mask_b,
               const float* __restrict__ dw_k, const float* __restrict__ bn_g,
               const float* __restrict__ bn_b, const float* __restrict__ bn_m,
               const float* __restrict__ bn_v,
               ushort_t* __restrict__ WtIn, ushort_t* __restrict__ WtOut,
               ushort_t* __restrict__ W2t, float* __restrict__ b2,
               float* __restrict__ dwkT, float* __restrict__ bnS,
               float* __restrict__ bnB)
{
    int bid = blockIdx.x;
    if (bid < NB * 260) {
        int n = bid / 260, rp = bid % 260;
        int h, w;
        if (rp < 66)       { h = 0;              w = rp; }
        else if (rp < 132) { h = 65;             w = rp - 66; }
        else if (rp < 196) { h = 1 + (rp - 132); w = 0; }
        else               { h = 1 + (rp - 196); w = 65; }
        xpadb[(size_t)((n * HI + h) * HI + w) * CCH + threadIdx.x] = 0;
        return;
    }
    int n = bid - NB * 260, k = threadIdx.x;
    WtIn [n * 256 + k] = f2bf(in_w [k * 256 + n]);
    WtOut[n * 256 + k] = f2bf(out_w[k * 256 + n]);
    float w2 = (n < 144) ? off_w[k * 144 + n]
             : (n < 216) ? mask_w[k * 72 + (n - 144)] : 0.f;
    W2t[n * 256 + k] = f2bf(w2);
    if (k == 0) b2[n] = (n < 144) ? off_b[n] : (n < 216) ? mask_b[n - 144] : 0.f;
    if (k < 9) dwkT[k * 256 + n] = dw_k[n * 9 + k];   // tap-major
    if (k == 9) {
        float s = bn_g[n] * rsqrtf(bn_v[n] + 1e-5f);
        bnS[n] = s;
        bnB[n] = bn_b[n] - bn_m[n] * s;
    }
}

// ---------------- depthwise 3x3 + BN + SiLU -> bf16 x1b, plus cast x -> xb ----
__global__ __launch_bounds__(256)
void dw_bn_silu(const float* __restrict__ x, const float* __restrict__ dwkT,
                const float* __restrict__ bnS, const float* __restrict__ bnB,
                ushort_t* __restrict__ x1b, ushort_t* __restrict__ xb)
{
    const int lane = threadIdx.x & 63, wid = threadIdx.x >> 6;
    const int pix = blockIdx.x * 4 + wid;
    const int n = pix >> 12, hw = pix & 4095, h = hw >> 6, w = hw & 63;
    const int c4 = lane << 2;

    const float4 cv = *reinterpret_cast<const float4*>(x + (size_t)pix * CCH + c4);
    ushort_t xo[4] = { f2bf(cv.x), f2bf(cv.y), f2bf(cv.z), f2bf(cv.w) };
    *reinterpret_cast<ushort4*>(xb + (size_t)pix * CCH + c4) = *reinterpret_cast<ushort4*>(xo);

    const float4 kc = *reinterpret_cast<const float4*>(dwkT + 4 * 256 + c4);
    float ax = cv.x * kc.x, ay = cv.y * kc.y, az = cv.z * kc.z, aw = cv.w * kc.w;

    #pragma unroll
    for (int tap = 0; tap < 9; ++tap) {
        if (tap == 4) continue;
        int hh = h + tap / 3 - 1, ww = w + tap % 3 - 1;
        if ((unsigned)hh < HH && (unsigned)ww < WW) {
            const float4 v = *reinterpret_cast<const float4*>(
                x + (size_t)((n * HH + hh) * WW + ww) * CCH + c4);
            const float4 kk = *reinterpret_cast<const float4*>(dwkT + tap * 256 + c4);
            ax += v.x * kk.x; ay += v.y * kk.y; az += v.z * kk.z; aw += v.w * kk.w;
        }
    }
    const float4 s = *reinterpret_cast<const float4*>(bnS + c4);
    const float4 b = *reinterpret_cast<const float4*>(bnB + c4);
    float yx = ax * s.x + b.x, yy = ay * s.y + b.y;
    float yz = az * s.z + b.z, yw = aw * s.w + b.w;
    yx = yx / (1.f + __expf(-yx));
    yy = yy / (1.f + __expf(-yy));
    yz = yz / (1.f + __expf(-yz));
    yw = yw / (1.f + __expf(-yw));
    ushort_t o[4] = { f2bf(yx), f2bf(yy), f2bf(yz), f2bf(yw) };
    *reinterpret_cast<ushort4*>(x1b + (size_t)pix * CCH + c4) = *reinterpret_cast<ushort4*>(o);
}

// ---------------- DCNv3 core: softmax + bilinear sampling on bf16 image -------
// 2 pixels per wave; lane (l=lane&31) owns group g=l>>2, 8 channels c8=(l&3)*8.
// offm is bf16.
__global__ __launch_bounds__(256)
void dcn_sample(const ushort_t* __restrict__ xpadb, const ushort_t* __restrict__ om,
                ushort_t* __restrict__ coreb)
{
    const int tid = threadIdx.x;
    const int pix = blockIdx.x * 8 + (tid >> 5);
    const int l   = tid & 31;
    const int g = l >> 2, c8 = (l & 3) << 3;
    const int n = pix >> 12, hw = pix & 4095, h = hw >> 6, w = hw & 63;
    const ushort_t* __restrict__ omp = om + (size_t)pix * OMWS;

    float lg[9], mx = -1e30f;
    #pragma unroll
    for (int p = 0; p < 9; ++p) { lg[p] = bf2f(omp[144 + g * 9 + p]); mx = fmaxf(mx, lg[p]); }
    float s = 0.f;
    #pragma unroll
    for (int p = 0; p < 9; ++p) { lg[p] = __expf(lg[p] - mx); s += lg[p]; }
    const float inv = 1.f / s;

    const ushort_t* __restrict__ img = xpadb + (size_t)n * HI * HI * CCH + g * CGC + c8;
    float acc[8] = {};
    #pragma unroll
    for (int p = 0; p < 9; ++p) {
        float ox = bf2f(omp[g * 18 + p * 2 + 0]);
        float oy = bf2f(omp[g * 18 + p * 2 + 1]);
        float xi = (float)(w + (p / 3)) + ox;
        float yi = (float)(h + (p % 3)) + oy;
        float x0f = floorf(xi), y0f = floorf(yi);
        int x0 = (int)x0f, y0 = (int)y0f;
        float fx = xi - x0f, fy = yi - y0f;
        float wgt = lg[p] * inv;
        float cw[4] = { (1.f - fx) * (1.f - fy) * wgt, fx * (1.f - fy) * wgt,
                        (1.f - fx) * fy * wgt,         fx * fy * wgt };
        #pragma unroll
        for (int cr = 0; cr < 4; ++cr) {
            int xc = x0 + (cr & 1), yc = y0 + (cr >> 1);
            if ((unsigned)xc < HI && (unsigned)yc < HI) {
                short8 raw = *reinterpret_cast<const short8*>(img + (size_t)(yc * HI + xc) * CCH);
                float wc = cw[cr];
                #pragma unroll
                for (int j = 0; j < 8; ++j) acc[j] += wc * bf2f((ushort_t)raw[j]);
            }
        }
    }
    ushort_t o[8];
    #pragma unroll
    for (int j = 0; j < 8; ++j) o[j] = f2bf(acc[j]);
    *reinterpret_cast<short8*>(coreb + (size_t)pix * CCH + g * CGC + c8) =
        *reinterpret_cast<short8*>(o);
}

extern "C" void kernel_launch(void* const* d_in, const int* in_sizes, int n_in,
                              void* d_out, int out_size, void* d_ws, size_t ws_size,
                              hipStream_t stream) {
    const float* x      = (const float*)d_in[0];
    const float* in_w   = (const float*)d_in[1];
    const float* in_b   = (const float*)d_in[2];
    const float* out_w  = (const float*)d_in[3];
    const float* out_b  = (const float*)d_in[4];
    const float* off_w  = (const float*)d_in[5];
    const float* off_b  = (const float*)d_in[6];
    const float* mask_w = (const float*)d_in[7];
    const float* mask_b = (const float*)d_in[8];
    const float* dw_k   = (const float*)d_in[9];
    const float* bn_g   = (const float*)d_in[10];
    const float* bn_b   = (const float*)d_in[11];
    const float* bn_m   = (const float*)d_in[12];
    const float* bn_v   = (const float*)d_in[13];

    ushort_t* xpadb = (ushort_t*)d_ws;                     // 4,460,544 us
    ushort_t* xb    = xpadb + 4460544;                     // 4,194,304 us
    ushort_t* x1b   = xb + 4194304;
    ushort_t* coreb = x1b + 4194304;
    ushort_t* offm  = coreb + 4194304;                     // 4,194,304 us (bf16)
    ushort_t* WtIn  = offm + 4194304;                      // 65,536 us
    ushort_t* WtOut = WtIn + 65536;
    ushort_t* W2t   = WtOut + 65536;
    float*    b2    = (float*)(W2t + 65536);               // 256 f
    float*    dwkT  = b2 + 256;                            // 9*256 f
    float*    bnS   = dwkT + 9 * 256;                      // 256 f
    float*    bnB   = bnS + 256;                           // 256 f

    // zero pad ring + pack all weights (one launch)
    ring_pack<<<NB * 260 + 256, 256, 0, stream>>>(xpadb,
        in_w, out_w, off_w, mask_w, off_b, mask_b,
        dw_k, bn_g, bn_b, bn_m, bn_v,
        WtIn, WtOut, W2t, b2, dwkT, bnS, bnB);

    // 1) depthwise conv + BN + SiLU -> x1b, and cast x -> xb (fused, float4)
    dw_bn_silu<<<NPIX / 4, 256, 0, stream>>>(x, dwkT, bnS, bnB, x1b, xb);

    // 2) input projection -> padded image interior (bf16 out)
    gemm_mfma<1><<<512, 256, 0, stream>>>(xb, WtIn, in_b, xpadb);

    // 3) offset + mask projection -> bf16 offm
    gemm_mfma<2><<<512, 256, 0, stream>>>(x1b, W2t, b2, offm);

    // 4) deformable sampling on bf16 image (2 px/wave, 16B gathers)
    dcn_sample<<<NPIX / 8, 256, 0, stream>>>(xpadb, offm, coreb);

    // 5) output projection -> d_out
    gemm_mfma<0><<<512, 256, 0, stream>>>(coreb, WtOut, out_b, (float*)d_out);
}